// Round 4
// baseline (22.644 us; speedup 1.0000x reference)
//
#include <hip/hip_runtime.h>

// LengthRegulator fused: B=16, T=512, D=384, DUR_MAX=8, MAX_OUT=3584
// out[b, j, :] = x[b, searchsorted_right(cumsum(dur[b]), j), :]  if j < total(b) else 0
//
// Round 4: same as round 3 but with native ext_vector_type(4) floats so
// __builtin_nontemporal_store compiles (HIP's float4 is a class type and is
// rejected by the builtin).

#define B_       16
#define T_       512
#define D_       384
#define MAX_OUT_ 3584            // T*(DUR_MAX-1)
#define ROW_F4   (D_ / 4)        // 96 float4 per row
#define ROWS_PB  32              // rows per block
#define BLK_PB   (MAX_OUT_ / ROWS_PB)        // 112 blocks per batch
#define NBLK     (BLK_PB * B_)               // 1792 total (divisible by 8 XCDs)
#define F4_PB    (ROWS_PB * ROW_F4)          // 3072 float4 per block

typedef float fx4 __attribute__((ext_vector_type(4)));

__global__ __launch_bounds__(256) void lr_fused_kernel(
    const fx4* __restrict__ x4, const int* __restrict__ dur,
    fx4* __restrict__ out4) {
  // ---- XCD-aware swizzle: consecutive swz ids land on the SAME XCD ----------
  const int bid = blockIdx.x;
  const int swz = (bid & 7) * (NBLK / 8) + (bid >> 3);
  const int b   = swz / BLK_PB;
  const int r0  = (swz - b * BLK_PB) * ROWS_PB;   // first output row
  const int t   = threadIdx.x;                    // 0..255

  __shared__ int ends[T_];                 // inclusive cumsum of dur[b]
  __shared__ int srcs[ROWS_PB];            // source frame per row (-1 = zero-fill)
  __shared__ int wsum[4];

  // ---- per-batch inclusive scan: 2 dur values per thread --------------------
  const int2 dd = ((const int2*)dur)[b * (T_ / 2) + t];  // dur[2t], dur[2t+1]
  int s = dd.x + dd.y;
  const int lane = t & 63;
  const int wave = t >> 6;                 // 0..3
  int v = s;
  #pragma unroll
  for (int off = 1; off < 64; off <<= 1) {
    int n = __shfl_up(v, off, 64);
    if (lane >= off) v += n;
  }
  if (lane == 63) wsum[wave] = v;
  __syncthreads();
  int wpre = 0;
  #pragma unroll
  for (int w = 0; w < 3; ++w)
    if (w < wave) wpre += wsum[w];
  const int e1 = v + wpre;                 // ends[2t+1]
  ends[2 * t]     = e1 - dd.y;             // ends[2t]
  ends[2 * t + 1] = e1;
  __syncthreads();

  // ---- searchsorted_right for this block's 32 rows --------------------------
  if (t < ROWS_PB) {
    const int j = r0 + t;
    int lo = 0;                            // #elements <= j
    #pragma unroll
    for (int step = 256; step > 0; step >>= 1)
      if (lo + step <= T_ && ends[lo + step - 1] <= j) lo += step;
    srcs[t] = (j < ends[T_ - 1]) ? lo : -1;
  }
  __syncthreads();

  // ---- flat coalesced copy: 12 float4 per thread, nt stores -----------------
  const fx4* __restrict__ xb = x4 + (size_t)b * T_ * ROW_F4;
  fx4* __restrict__ ob = out4 + ((size_t)b * MAX_OUT_ + r0) * ROW_F4;
  #pragma unroll
  for (int k = 0; k < F4_PB / 256; ++k) {
    const int idx = k * 256 + t;           // 0..3071
    const int rl  = idx / ROW_F4;          // local row 0..31
    const int col = idx - rl * ROW_F4;     // 0..95
    const int src = srcs[rl];
    fx4 val = (fx4)(0.f);
    if (src >= 0) val = xb[src * ROW_F4 + col];
    __builtin_nontemporal_store(val, &ob[idx]);
  }
}

extern "C" void kernel_launch(void* const* d_in, const int* in_sizes, int n_in,
                              void* d_out, int out_size, void* d_ws, size_t ws_size,
                              hipStream_t stream) {
  const float* x   = (const float*)d_in[0];   // (B, T, D) fp32
  const int*   dur = (const int*)d_in[1];     // (B, T) int32
  float* out = (float*)d_out;                 // (B, MAX_OUT, D) fp32

  lr_fused_kernel<<<NBLK, 256, 0, stream>>>(
      (const fx4*)x, dur, (fx4*)out);
}

// Round 5
// 20.677 us; speedup vs baseline: 1.0951x; 1.0951x over previous
//
#include <hip/hip_runtime.h>

// LengthRegulator fused: B=16, T=512, D=384, DUR_MAX=8, MAX_OUT=3584
// out[b, j, :] = x[b, searchsorted_right(cumsum(dur[b]), j), :]  if j < total(b) else 0
//
// Round 5: revert round-3/4 (XCD swizzle ~-2% when L3-fit; nt-stores defeat L2
// write-combining -> +12% regression). Single change vs round-2 baseline:
// ROWS_PB 32 -> 64 (896 blocks instead of 1792) to halve the redundant
// per-block cumsum prologue. Copy loop structure unchanged.

#define B_       16
#define T_       512
#define D_       384
#define MAX_OUT_ 3584            // T*(DUR_MAX-1)
#define ROW_F4   (D_ / 4)        // 96 float4 per row
#define ROWS_PB  64              // rows per block -> 56 x 16 = 896 blocks
#define BLK_PB   (MAX_OUT_ / ROWS_PB)        // 56 blocks per batch
#define F4_PB    (ROWS_PB * ROW_F4)          // 6144 float4 per block -> 24/thread

__global__ __launch_bounds__(256) void lr_fused_kernel(
    const float4* __restrict__ x4, const int* __restrict__ dur,
    float4* __restrict__ out4) {
  const int b  = blockIdx.y;
  const int r0 = blockIdx.x * ROWS_PB;     // first output row of this block
  const int t  = threadIdx.x;              // 0..255

  __shared__ int ends[T_];                 // inclusive cumsum of dur[b]
  __shared__ int srcs[ROWS_PB];            // source frame per row (-1 = zero-fill)
  __shared__ int wsum[4];

  // ---- per-batch inclusive scan: 2 dur values per thread --------------------
  const int2 dd = ((const int2*)dur)[b * (T_ / 2) + t];  // dur[2t], dur[2t+1]
  int s = dd.x + dd.y;
  const int lane = t & 63;
  const int wave = t >> 6;                 // 0..3
  int v = s;
  #pragma unroll
  for (int off = 1; off < 64; off <<= 1) {
    int n = __shfl_up(v, off, 64);
    if (lane >= off) v += n;
  }
  if (lane == 63) wsum[wave] = v;
  __syncthreads();
  int wpre = 0;
  #pragma unroll
  for (int w = 0; w < 3; ++w)
    if (w < wave) wpre += wsum[w];
  const int e1 = v + wpre;                 // ends[2t+1]
  ends[2 * t]     = e1 - dd.y;             // ends[2t]
  ends[2 * t + 1] = e1;
  __syncthreads();

  // ---- searchsorted_right for this block's 64 rows --------------------------
  if (t < ROWS_PB) {
    const int j = r0 + t;
    int lo = 0;                            // #elements <= j
    #pragma unroll
    for (int step = 256; step > 0; step >>= 1)
      if (lo + step <= T_ && ends[lo + step - 1] <= j) lo += step;
    srcs[t] = (j < ends[T_ - 1]) ? lo : -1;
  }
  __syncthreads();

  // ---- flat coalesced copy: 24 float4 per thread ----------------------------
  const float4* __restrict__ xb = x4 + (size_t)b * T_ * ROW_F4;
  float4* __restrict__ ob = out4 + ((size_t)b * MAX_OUT_ + r0) * ROW_F4;
  #pragma unroll
  for (int k = 0; k < F4_PB / 256; ++k) {
    const int idx = k * 256 + t;           // 0..6143
    const int rl  = idx / ROW_F4;          // local row 0..63
    const int col = idx - rl * ROW_F4;     // 0..95
    const int src = srcs[rl];
    float4 val = make_float4(0.f, 0.f, 0.f, 0.f);
    if (src >= 0) val = xb[src * ROW_F4 + col];
    ob[idx] = val;
  }
}

extern "C" void kernel_launch(void* const* d_in, const int* in_sizes, int n_in,
                              void* d_out, int out_size, void* d_ws, size_t ws_size,
                              hipStream_t stream) {
  const float* x   = (const float*)d_in[0];   // (B, T, D) fp32
  const int*   dur = (const int*)d_in[1];     // (B, T) int32
  float* out = (float*)d_out;                 // (B, MAX_OUT, D) fp32

  dim3 grid(BLK_PB, B_);                      // (56, 16)
  lr_fused_kernel<<<grid, 256, 0, stream>>>(
      (const float4*)x, dur, (float4*)out);
}